// Round 3
// baseline (105.027 us; speedup 1.0000x reference)
//
#include <hip/hip_runtime.h>

// VNCMDLoss: single fused kernel, masked multi-reduction.
//  0 recon_real  (B,T)   f32      4 arrays x 8 MiB
//  1 recon_imag  (B,T)   f32
//  2 target_real (B,T)   f32
//  3 target_imag (B,T)   f32
//  4 eIF         (B,N,T) f32      64 MiB (masked rows skipped)
//  5 target_if   (B,N,T) f32      64 MiB (masked rows skipped)
//  6 mode_mask   (B,N)   i32
// Output: 4 x f32: total_loss, recon_loss, if_loss, smooth_loss
//
// Design:
//  - No FP64 global atomics (CAS-loop serialization was 2x: R1 53us -> R2 26us).
//  - Each block stores its partial pair to a private d_ws slot; the LAST block
//    (threadfence+ticket) reduces all 2x2560 partials and writes the 4 outputs,
//    removing the second kernel launch from the graph.
//  - Loads batched 8-wide per step so ~8 float4 loads are in flight per thread
//    (R1 showed VGPR=20 => single load in flight => latency-serialized).
//  - IF part: each thread owns 4 CONSECUTIVE float4s (16 scalars) => 15/16
//    smooth diffs are in-register; one __shfl_down + lane63 fixup per batch.

namespace {
constexpr int    kB = 8;
constexpr int    kN = 8;
constexpr int    kT = 262144;
constexpr long long kBT  = (long long)kB * kT;        // 2,097,152
constexpr long long kBNT = (long long)kB * kN * kT;   // 16,777,216

constexpr int THREADS      = 256;
constexpr int RECON_BLOCKS = 512;               // 131072 threads, 4 float4/array each
constexpr int SEGS         = 32;                // segments per (b,n) row
constexpr int IF_BLOCKS    = kB * kN * SEGS;    // 2048
constexpr int TOTAL_BLOCKS = RECON_BLOCKS + IF_BLOCKS;  // 2560

constexpr double LAMBDA_IF     = 0.5;
constexpr double LAMBDA_SMOOTH = 0.1;

constexpr int TICKET_OFF_DBL = 2 * TOTAL_BLOCKS;  // ticket lives after partials
}

__device__ __forceinline__ float sq(float x) { return x * x; }

// Reduce two float partials across the block; thread 0 stores both (as double).
__device__ __forceinline__ void block_reduce2_store(float a, float b, double* dst) {
    double da = (double)a, db = (double)b;
    #pragma unroll
    for (int o = 32; o > 0; o >>= 1) {
        da += __shfl_down(da, o, 64);
        db += __shfl_down(db, o, 64);
    }
    __shared__ double lds[8];
    const int lane = threadIdx.x & 63;
    const int wid  = threadIdx.x >> 6;      // 4 waves per block
    if (lane == 0) { lds[wid] = da; lds[wid + 4] = db; }
    __syncthreads();
    if (threadIdx.x == 0) {
        dst[0] = lds[0] + lds[1] + lds[2] + lds[3];
        dst[1] = lds[4] + lds[5] + lds[6] + lds[7];
    }
}

__global__ __launch_bounds__(THREADS)
void vncmd_fused_kernel(const float* __restrict__ rr, const float* __restrict__ ri,
                        const float* __restrict__ tr, const float* __restrict__ ti,
                        const float* __restrict__ eIF, const float* __restrict__ tIF,
                        const int* __restrict__ mask, double* __restrict__ ws,
                        unsigned int* __restrict__ ticket, float* __restrict__ out) {
    const int bid = blockIdx.x;
    const int tid = threadIdx.x;

    if (bid < RECON_BLOCKS) {
        // ---- recon: sum (rr-tr)^2 and (ri-ti)^2 over B*T, strided float4 ----
        constexpr int STRIDE = RECON_BLOCKS * THREADS;   // 131072
        const int base = bid * THREADS + tid;
        const float4* rr4 = (const float4*)rr;
        const float4* tr4 = (const float4*)tr;
        const float4* ri4 = (const float4*)ri;
        const float4* ti4 = (const float4*)ti;
        float a0 = 0.f, a1 = 0.f;
        #pragma unroll
        for (int h = 0; h < 2; ++h) {
            const int v0 = base + (2 * h) * STRIDE;
            const int v1 = base + (2 * h + 1) * STRIDE;
            float4 x0 = rr4[v0], y0 = tr4[v0], x1 = rr4[v1], y1 = tr4[v1];
            float4 u0 = ri4[v0], w0 = ti4[v0], u1 = ri4[v1], w1 = ti4[v1];
            a0 += sq(x0.x - y0.x) + sq(x0.y - y0.y) + sq(x0.z - y0.z) + sq(x0.w - y0.w)
                + sq(x1.x - y1.x) + sq(x1.y - y1.y) + sq(x1.z - y1.z) + sq(x1.w - y1.w);
            a1 += sq(u0.x - w0.x) + sq(u0.y - w0.y) + sq(u0.z - w0.z) + sq(u0.w - w0.w)
                + sq(u1.x - w1.x) + sq(u1.y - w1.y) + sq(u1.z - w1.z) + sq(u1.w - w1.w);
        }
        block_reduce2_store(a0, a1, ws + 2 * bid);
    } else {
        // ---- IF part: one block = one (row, segment); 16 consecutive scalars/thread ----
        const int ib  = bid - RECON_BLOCKS;
        const int row = ib >> 5;             // / SEGS
        const int seg = ib & (SEGS - 1);
        double* dst = ws + 2 * bid;
        if (mask[row] == 1) {
            const float4* e4 = (const float4*)(eIF + (size_t)row * kT);
            const float4* t4 = (const float4*)(tIF + (size_t)row * kT);
            constexpr int VPR = kT / 4;      // 65536 vectors per row
            constexpr int VPS = 2048;        // vectors per segment
            const int v0 = seg * VPS;
            const bool lane63 = (tid & 63) == 63;
            float a2 = 0.f, a3 = 0.f;
            #pragma unroll
            for (int r = 0; r < 2; ++r) {
                const int vb = v0 + r * 1024 + tid * 4;
                float4 e0 = e4[vb], e1 = e4[vb + 1], e2 = e4[vb + 2], e3 = e4[vb + 3];
                float4 q0 = t4[vb], q1 = t4[vb + 1], q2 = t4[vb + 2], q3 = t4[vb + 3];
                a2 += sq(e0.x - q0.x) + sq(e0.y - q0.y) + sq(e0.z - q0.z) + sq(e0.w - q0.w)
                    + sq(e1.x - q1.x) + sq(e1.y - q1.y) + sq(e1.z - q1.z) + sq(e1.w - q1.w)
                    + sq(e2.x - q2.x) + sq(e2.y - q2.y) + sq(e2.z - q2.z) + sq(e2.w - q2.w)
                    + sq(e3.x - q3.x) + sq(e3.y - q3.y) + sq(e3.z - q3.z) + sq(e3.w - q3.w);
                a3 += sq(e0.y - e0.x) + sq(e0.z - e0.y) + sq(e0.w - e0.z)
                    + sq(e1.x - e0.w) + sq(e1.y - e1.x) + sq(e1.z - e1.y) + sq(e1.w - e1.z)
                    + sq(e2.x - e1.w) + sq(e2.y - e2.x) + sq(e2.z - e2.y) + sq(e2.w - e2.z)
                    + sq(e3.x - e2.w) + sq(e3.y - e3.x) + sq(e3.z - e3.y) + sq(e3.w - e3.z);
                // boundary diff to the next 16-scalar chunk (next thread's e0.x)
                float nx = __shfl_down(e0.x, 1, 64);
                if (lane63) nx = (vb + 4 < VPR) ? e4[vb + 4].x : e3.w;  // row end -> 0 term
                a3 += sq(nx - e3.w);
            }
            block_reduce2_store(a2, a3, dst);
        } else {
            if (tid == 0) { dst[0] = 0.0; dst[1] = 0.0; }
        }
    }

    // ---- last-block finalize (threadfence + ticket) ----
    __shared__ int is_last;
    if (tid == 0) {
        __threadfence();
        unsigned int old = atomicAdd(ticket, 1u);
        is_last = (old == (unsigned int)(TOTAL_BLOCKS - 1)) ? 1 : 0;
    }
    __syncthreads();
    if (!is_last) return;
    __threadfence();

    double s0 = 0.0, s1 = 0.0, s2 = 0.0, s3 = 0.0;
    for (int i = tid; i < TOTAL_BLOCKS; i += THREADS) {
        double p = ws[2 * i], q = ws[2 * i + 1];
        if (i < RECON_BLOCKS) { s0 += p; s1 += q; }
        else                  { s2 += p; s3 += q; }
    }
    #pragma unroll
    for (int o = 32; o > 0; o >>= 1) {
        s0 += __shfl_down(s0, o, 64);
        s1 += __shfl_down(s1, o, 64);
        s2 += __shfl_down(s2, o, 64);
        s3 += __shfl_down(s3, o, 64);
    }
    __shared__ double lds2[4][4];
    const int lane = tid & 63;
    const int wid  = tid >> 6;
    if (lane == 0) { lds2[wid][0] = s0; lds2[wid][1] = s1; lds2[wid][2] = s2; lds2[wid][3] = s3; }
    __syncthreads();
    if (tid == 0) {
        double t0 = lds2[0][0] + lds2[1][0] + lds2[2][0] + lds2[3][0];
        double t1 = lds2[0][1] + lds2[1][1] + lds2[2][1] + lds2[3][1];
        double t2 = lds2[0][2] + lds2[1][2] + lds2[2][2] + lds2[3][2];
        double t3 = lds2[0][3] + lds2[1][3] + lds2[2][3] + lds2[3][3];
        int c = 0;
        #pragma unroll
        for (int i = 0; i < kB * kN; ++i) c += (mask[i] == 1);
        double count = (double)c;
        double recon = t0 / (double)kBT + t1 / (double)kBT;
        double ifl   = t2 / (double)kBNT;
        double denom = (count > 1.0 ? count : 1.0) * (double)(kT - 1);
        double smooth = t3 / denom;
        double total = recon + LAMBDA_IF * ifl + (count > 0.0 ? LAMBDA_SMOOTH * smooth : 0.0);
        out[0] = (float)total;
        out[1] = (float)recon;
        out[2] = (float)ifl;
        out[3] = (float)smooth;
    }
}

extern "C" void kernel_launch(void* const* d_in, const int* in_sizes, int n_in,
                              void* d_out, int out_size, void* d_ws, size_t ws_size,
                              hipStream_t stream) {
    const float* rr  = (const float*)d_in[0];
    const float* ri  = (const float*)d_in[1];
    const float* tr  = (const float*)d_in[2];
    const float* ti  = (const float*)d_in[3];
    const float* eIF = (const float*)d_in[4];
    const float* tIF = (const float*)d_in[5];
    const int*   msk = (const int*)d_in[6];
    float* out = (float*)d_out;
    double* ws = (double*)d_ws;
    unsigned int* ticket = (unsigned int*)(ws + TICKET_OFF_DBL);

    hipMemsetAsync(ticket, 0, sizeof(unsigned int), stream);   // graph-legal memset node
    vncmd_fused_kernel<<<TOTAL_BLOCKS, THREADS, 0, stream>>>(
        rr, ri, tr, ti, eIF, tIF, msk, ws, ticket, out);
}

// Round 4
// 33.331 us; speedup vs baseline: 3.1511x; 3.1511x over previous
//
#include <hip/hip_runtime.h>

// VNCMDLoss: two-stage masked multi-reduction (R2 structure + deep load batching).
//  0 recon_real  (B,T)   f32      4 arrays x 8 MiB
//  1 recon_imag  (B,T)   f32
//  2 target_real (B,T)   f32
//  3 target_imag (B,T)   f32
//  4 eIF         (B,N,T) f32      64 MiB (masked rows skipped entirely)
//  5 target_if   (B,N,T) f32      64 MiB (masked rows skipped entirely)
//  6 mode_mask   (B,N)   i32
// Output: 4 x f32: total_loss, recon_loss, if_loss, smooth_loss
//
// Lessons encoded here:
//  - R1->R2: FP64 atomicAdd = contended CAS loop, 2x cost. Use per-block stores.
//  - R3: single-kernel fusion via __threadfence+ticket = agent-scope fence =>
//    per-block L2 writeback on non-coherent XCD L2s => 150us kernel. NEVER fuse
//    cross-block reduction with fences here; the kernel boundary is the sync.
//  - Coalescing: lane i must read vector (base + i); thread-owned CONSECUTIVE
//    chunks (R3) de-coalesce to 64B lane stride.
//  - This round: batch loads 8-deep (textually before uses) for load-latency ILP.

namespace {
constexpr int    kB = 8;
constexpr int    kN = 8;
constexpr int    kT = 262144;
constexpr long long kBT  = (long long)kB * kT;        // 2,097,152
constexpr long long kBNT = (long long)kB * kN * kT;   // 16,777,216

constexpr int THREADS      = 256;
constexpr int RECON_BLOCKS = 512;               // 4 float4/thread/array, exact
constexpr int SEGS         = 32;                // segments per (b,n) row
constexpr int IF_BLOCKS    = kB * kN * SEGS;    // 2048
constexpr int TOTAL_BLOCKS = RECON_BLOCKS + IF_BLOCKS;  // 2560

constexpr double LAMBDA_IF     = 0.5;
constexpr double LAMBDA_SMOOTH = 0.1;
}

__device__ __forceinline__ float sq(float x) { return x * x; }

// Reduce two float partials across the block; thread 0 stores both (as double).
__device__ __forceinline__ void block_reduce2_store(float a, float b, double* dst) {
    double da = (double)a, db = (double)b;
    #pragma unroll
    for (int o = 32; o > 0; o >>= 1) {
        da += __shfl_down(da, o, 64);
        db += __shfl_down(db, o, 64);
    }
    __shared__ double lds[8];
    const int lane = threadIdx.x & 63;
    const int wid  = threadIdx.x >> 6;      // 4 waves per block
    if (lane == 0) { lds[wid] = da; lds[wid + 4] = db; }
    __syncthreads();
    if (threadIdx.x == 0) {
        dst[0] = lds[0] + lds[1] + lds[2] + lds[3];
        dst[1] = lds[4] + lds[5] + lds[6] + lds[7];
    }
}

__global__ __launch_bounds__(THREADS)
void vncmd_main_kernel(const float* __restrict__ rr, const float* __restrict__ ri,
                       const float* __restrict__ tr, const float* __restrict__ ti,
                       const float* __restrict__ eIF, const float* __restrict__ tIF,
                       const int* __restrict__ mask, double* __restrict__ ws) {
    const int bid = blockIdx.x;
    const int tid = threadIdx.x;

    if (bid < RECON_BLOCKS) {
        // ---- recon: sum (rr-tr)^2 and (ri-ti)^2 over B*T; coalesced, 8 loads in flight ----
        constexpr int STRIDE = RECON_BLOCKS * THREADS;   // 131072 float4
        const int base = bid * THREADS + tid;
        const float4* rr4 = (const float4*)rr;
        const float4* tr4 = (const float4*)tr;
        const float4* ri4 = (const float4*)ri;
        const float4* ti4 = (const float4*)ti;
        const int v0 = base, v1 = base + STRIDE, v2 = base + 2 * STRIDE, v3 = base + 3 * STRIDE;

        // batch 1: real pair (8 loads issued back-to-back)
        float4 x0 = rr4[v0], x1 = rr4[v1], x2 = rr4[v2], x3 = rr4[v3];
        float4 y0 = tr4[v0], y1 = tr4[v1], y2 = tr4[v2], y3 = tr4[v3];
        // batch 2: imag pair
        float4 u0 = ri4[v0], u1 = ri4[v1], u2 = ri4[v2], u3 = ri4[v3];
        float4 w0 = ti4[v0], w1 = ti4[v1], w2 = ti4[v2], w3 = ti4[v3];

        float a0 = sq(x0.x - y0.x) + sq(x0.y - y0.y) + sq(x0.z - y0.z) + sq(x0.w - y0.w)
                 + sq(x1.x - y1.x) + sq(x1.y - y1.y) + sq(x1.z - y1.z) + sq(x1.w - y1.w)
                 + sq(x2.x - y2.x) + sq(x2.y - y2.y) + sq(x2.z - y2.z) + sq(x2.w - y2.w)
                 + sq(x3.x - y3.x) + sq(x3.y - y3.y) + sq(x3.z - y3.z) + sq(x3.w - y3.w);
        float a1 = sq(u0.x - w0.x) + sq(u0.y - w0.y) + sq(u0.z - w0.z) + sq(u0.w - w0.w)
                 + sq(u1.x - w1.x) + sq(u1.y - w1.y) + sq(u1.z - w1.z) + sq(u1.w - w1.w)
                 + sq(u2.x - w2.x) + sq(u2.y - w2.y) + sq(u2.z - w2.z) + sq(u2.w - w2.w)
                 + sq(u3.x - w3.x) + sq(u3.y - w3.y) + sq(u3.z - w3.z) + sq(u3.w - w3.w);
        block_reduce2_store(a0, a1, ws + 2 * bid);
    } else {
        // ---- IF part: one block = one (row, segment); coalesced stride-THREADS ----
        const int ib  = bid - RECON_BLOCKS;
        const int row = ib >> 5;             // / SEGS
        const int seg = ib & (SEGS - 1);
        double* dst = ws + 2 * bid;
        if (mask[row] != 1) {                // masked row contributes 0; skip all reads
            if (tid == 0) { dst[0] = 0.0; dst[1] = 0.0; }
            return;
        }

        const float4* e4 = (const float4*)(eIF + (size_t)row * kT);
        const float4* t4 = (const float4*)(tIF + (size_t)row * kT);
        constexpr int VPR = kT / 4;          // 65536 vectors per row
        constexpr int VPS = 2048;            // vectors per segment (8 per thread)
        const int v0 = seg * VPS + tid;
        const bool lane63 = (tid & 63) == 63;

        float a2 = 0.f, a3 = 0.f;
        #pragma unroll
        for (int h = 0; h < 2; ++h) {
            const int b0 = v0 + (4 * h) * THREADS;
            const int b1 = b0 + THREADS, b2 = b0 + 2 * THREADS, b3 = b0 + 3 * THREADS;
            // 8 loads issued back-to-back
            float4 e0 = e4[b0], e1 = e4[b1], e2 = e4[b2], e3 = e4[b3];
            float4 q0 = t4[b0], q1 = t4[b1], q2 = t4[b2], q3 = t4[b3];
            // lane63 boundary scalars (divergent, 4 loads, L1/L2 hits)
            float n0 = 0.f, n1 = 0.f, n2 = 0.f, n3 = 0.f;
            if (lane63) {
                n0 = (b0 + 1 < VPR) ? e4[b0 + 1].x : e0.w;
                n1 = (b1 + 1 < VPR) ? e4[b1 + 1].x : e1.w;
                n2 = (b2 + 1 < VPR) ? e4[b2 + 1].x : e2.w;
                n3 = (b3 + 1 < VPR) ? e4[b3 + 1].x : e3.w;
            }
            a2 += sq(e0.x - q0.x) + sq(e0.y - q0.y) + sq(e0.z - q0.z) + sq(e0.w - q0.w)
                + sq(e1.x - q1.x) + sq(e1.y - q1.y) + sq(e1.z - q1.z) + sq(e1.w - q1.w)
                + sq(e2.x - q2.x) + sq(e2.y - q2.y) + sq(e2.z - q2.z) + sq(e2.w - q2.w)
                + sq(e3.x - q3.x) + sq(e3.y - q3.y) + sq(e3.z - q3.z) + sq(e3.w - q3.w);
            // in-vector smooth diffs
            a3 += sq(e0.y - e0.x) + sq(e0.z - e0.y) + sq(e0.w - e0.z)
                + sq(e1.y - e1.x) + sq(e1.z - e1.y) + sq(e1.w - e1.z)
                + sq(e2.y - e2.x) + sq(e2.z - e2.y) + sq(e2.w - e2.z)
                + sq(e3.y - e3.x) + sq(e3.z - e3.y) + sq(e3.w - e3.z);
            // cross-vector diffs: neighbor lane holds the next vector's .x
            float s0 = __shfl_down(e0.x, 1, 64);
            float s1 = __shfl_down(e1.x, 1, 64);
            float s2 = __shfl_down(e2.x, 1, 64);
            float s3 = __shfl_down(e3.x, 1, 64);
            if (lane63) { s0 = n0; s1 = n1; s2 = n2; s3 = n3; }
            a3 += sq(s0 - e0.w) + sq(s1 - e1.w) + sq(s2 - e2.w) + sq(s3 - e3.w);
        }
        block_reduce2_store(a2, a3, dst);
    }
}

// Single-wave finalize: reduce 2*2560 doubles, write the 4 outputs.
__global__ __launch_bounds__(64)
void finalize_kernel(const double* __restrict__ ws,
                     const int* __restrict__ mask,
                     float* __restrict__ out) {
    const int lane = threadIdx.x;
    double s0 = 0.0, s1 = 0.0, s2 = 0.0, s3 = 0.0;
    for (int i = lane; i < RECON_BLOCKS; i += 64) {
        s0 += ws[2 * i];
        s1 += ws[2 * i + 1];
    }
    const double* w2 = ws + 2 * RECON_BLOCKS;
    for (int i = lane; i < IF_BLOCKS; i += 64) {
        s2 += w2[2 * i];
        s3 += w2[2 * i + 1];
    }
    #pragma unroll
    for (int o = 32; o > 0; o >>= 1) {
        s0 += __shfl_down(s0, o, 64);
        s1 += __shfl_down(s1, o, 64);
        s2 += __shfl_down(s2, o, 64);
        s3 += __shfl_down(s3, o, 64);
    }
    if (lane == 0) {
        int c = 0;
        #pragma unroll
        for (int i = 0; i < kB * kN; ++i) c += (mask[i] == 1);
        double count = (double)c;
        double recon = s0 / (double)kBT + s1 / (double)kBT;
        double ifl   = s2 / (double)kBNT;
        double denom = (count > 1.0 ? count : 1.0) * (double)(kT - 1);
        double smooth = s3 / denom;
        double total = recon + LAMBDA_IF * ifl + (count > 0.0 ? LAMBDA_SMOOTH * smooth : 0.0);
        out[0] = (float)total;
        out[1] = (float)recon;
        out[2] = (float)ifl;
        out[3] = (float)smooth;
    }
}

extern "C" void kernel_launch(void* const* d_in, const int* in_sizes, int n_in,
                              void* d_out, int out_size, void* d_ws, size_t ws_size,
                              hipStream_t stream) {
    const float* rr  = (const float*)d_in[0];
    const float* ri  = (const float*)d_in[1];
    const float* tr  = (const float*)d_in[2];
    const float* ti  = (const float*)d_in[3];
    const float* eIF = (const float*)d_in[4];
    const float* tIF = (const float*)d_in[5];
    const int*   msk = (const int*)d_in[6];
    float* out = (float*)d_out;
    double* ws = (double*)d_ws;

    vncmd_main_kernel<<<TOTAL_BLOCKS, THREADS, 0, stream>>>(
        rr, ri, tr, ti, eIF, tIF, msk, ws);
    finalize_kernel<<<1, 64, 0, stream>>>(ws, msk, out);
}

// Round 5
// 25.029 us; speedup vs baseline: 4.1962x; 1.3317x over previous
//
#include <hip/hip_runtime.h>

// VNCMDLoss: two-stage masked multi-reduction, persistent-grid stage 1.
//  0 recon_real  (B,T)   f32      4 arrays x 8 MiB
//  1 recon_imag  (B,T)   f32
//  2 target_real (B,T)   f32
//  3 target_imag (B,T)   f32
//  4 eIF         (B,N,T) f32      64 MiB (masked rows skipped entirely)
//  5 target_if   (B,N,T) f32      64 MiB (masked rows skipped entirely)
//  6 mode_mask   (B,N)   i32
// Output: 4 x f32: total_loss, recon_loss, if_loss, smooth_loss
//
// Lessons encoded:
//  - R1->R2: FP64 atomicAdd = contended CAS loop (2x). Per-block stores instead.
//  - R3: __threadfence+ticket fusion = per-block L2 writeback on non-coherent
//    XCD L2s => 150us. Kernel boundary IS the sync; never fence here.
//  - R4: single-WAVE finalize = ~80 latency-serialized loads on one CU (+7us).
//    Finalize needs >=256 threads.
//  - R5 (this): 2560-block grid = 10240 waves > 8192 slots = second dispatch
//    round = ~40% tail. Persistent 1024-block grid (4096 waves, all resident,
//    __launch_bounds__(256,4)) loops units; mask cached in LDS per block.

namespace {
constexpr int    kB = 8;
constexpr int    kN = 8;
constexpr int    kT = 262144;
constexpr long long kBT  = (long long)kB * kT;        // 2,097,152
constexpr long long kBNT = (long long)kB * kN * kT;   // 16,777,216

constexpr int THREADS     = 256;
constexpr int RECON_UNITS = 512;                 // 4 float4/thread/array, exact
constexpr int SEGS        = 32;                  // segments per (b,n) row
constexpr int IF_UNITS    = kB * kN * SEGS;      // 2048
constexpr int TOTAL_UNITS = RECON_UNITS + IF_UNITS;  // 2560
constexpr int GRID        = 1024;                // 4096 waves = 4/SIMD, one round

constexpr double LAMBDA_IF     = 0.5;
constexpr double LAMBDA_SMOOTH = 0.1;
}

__device__ __forceinline__ float sq(float x) { return x * x; }

// Reduce two float partials across the block; thread 0 stores both (as double).
// Trailing __syncthreads protects LDS reuse across persistent-loop iterations.
__device__ __forceinline__ void block_reduce2_store(float a, float b, double* dst) {
    double da = (double)a, db = (double)b;
    #pragma unroll
    for (int o = 32; o > 0; o >>= 1) {
        da += __shfl_down(da, o, 64);
        db += __shfl_down(db, o, 64);
    }
    __shared__ double lds[8];
    const int lane = threadIdx.x & 63;
    const int wid  = threadIdx.x >> 6;      // 4 waves per block
    if (lane == 0) { lds[wid] = da; lds[wid + 4] = db; }
    __syncthreads();
    if (threadIdx.x == 0) {
        dst[0] = lds[0] + lds[1] + lds[2] + lds[3];
        dst[1] = lds[4] + lds[5] + lds[6] + lds[7];
    }
    __syncthreads();
}

__global__ __launch_bounds__(THREADS, 4)
void vncmd_main_kernel(const float* __restrict__ rr, const float* __restrict__ ri,
                       const float* __restrict__ tr, const float* __restrict__ ti,
                       const float* __restrict__ eIF, const float* __restrict__ tIF,
                       const int* __restrict__ mask, double* __restrict__ ws) {
    const int tid = threadIdx.x;

    __shared__ int smask[kB * kN];
    if (tid < kB * kN) smask[tid] = mask[tid];
    __syncthreads();

    for (int u = blockIdx.x; u < TOTAL_UNITS; u += GRID) {
        if (u < RECON_UNITS) {
            // ---- recon: coalesced strided float4, 16 loads in flight ----
            constexpr int STRIDE = RECON_UNITS * THREADS;   // 131072 float4
            const int base = u * THREADS + tid;
            const float4* rr4 = (const float4*)rr;
            const float4* tr4 = (const float4*)tr;
            const float4* ri4 = (const float4*)ri;
            const float4* ti4 = (const float4*)ti;
            const int v0 = base, v1 = base + STRIDE, v2 = base + 2 * STRIDE, v3 = base + 3 * STRIDE;

            float4 x0 = rr4[v0], x1 = rr4[v1], x2 = rr4[v2], x3 = rr4[v3];
            float4 y0 = tr4[v0], y1 = tr4[v1], y2 = tr4[v2], y3 = tr4[v3];
            float4 u0 = ri4[v0], u1 = ri4[v1], u2 = ri4[v2], u3 = ri4[v3];
            float4 w0 = ti4[v0], w1 = ti4[v1], w2 = ti4[v2], w3 = ti4[v3];

            float a0 = sq(x0.x - y0.x) + sq(x0.y - y0.y) + sq(x0.z - y0.z) + sq(x0.w - y0.w)
                     + sq(x1.x - y1.x) + sq(x1.y - y1.y) + sq(x1.z - y1.z) + sq(x1.w - y1.w)
                     + sq(x2.x - y2.x) + sq(x2.y - y2.y) + sq(x2.z - y2.z) + sq(x2.w - y2.w)
                     + sq(x3.x - y3.x) + sq(x3.y - y3.y) + sq(x3.z - y3.z) + sq(x3.w - y3.w);
            float a1 = sq(u0.x - w0.x) + sq(u0.y - w0.y) + sq(u0.z - w0.z) + sq(u0.w - w0.w)
                     + sq(u1.x - w1.x) + sq(u1.y - w1.y) + sq(u1.z - w1.z) + sq(u1.w - w1.w)
                     + sq(u2.x - w2.x) + sq(u2.y - w2.y) + sq(u2.z - w2.z) + sq(u2.w - w2.w)
                     + sq(u3.x - w3.x) + sq(u3.y - w3.y) + sq(u3.z - w3.z) + sq(u3.w - w3.w);
            block_reduce2_store(a0, a1, ws + 2 * u);
        } else {
            // ---- IF part: unit = (row, segment); coalesced stride-THREADS ----
            const int iu  = u - RECON_UNITS;
            const int row = iu >> 5;             // / SEGS
            const int seg = iu & (SEGS - 1);
            double* dst = ws + 2 * u;
            if (smask[row] != 1) {               // uniform per block; contributes 0
                if (tid == 0) { dst[0] = 0.0; dst[1] = 0.0; }
                continue;
            }

            const float4* e4 = (const float4*)(eIF + (size_t)row * kT);
            const float4* t4 = (const float4*)(tIF + (size_t)row * kT);
            constexpr int VPR = kT / 4;          // 65536 vectors per row
            constexpr int VPS = 2048;            // vectors per segment (8/thread)
            const int v0 = seg * VPS + tid;
            const bool lane63 = (tid & 63) == 63;

            float a2 = 0.f, a3 = 0.f;
            #pragma unroll
            for (int h = 0; h < 2; ++h) {
                const int b0 = v0 + (4 * h) * THREADS;
                const int b1 = b0 + THREADS, b2 = b0 + 2 * THREADS, b3 = b0 + 3 * THREADS;
                float4 e0 = e4[b0], e1 = e4[b1], e2 = e4[b2], e3 = e4[b3];
                float4 q0 = t4[b0], q1 = t4[b1], q2 = t4[b2], q3 = t4[b3];
                float n0 = 0.f, n1 = 0.f, n2 = 0.f, n3 = 0.f;
                if (lane63) {                    // wave-edge boundary scalars
                    n0 = (b0 + 1 < VPR) ? e4[b0 + 1].x : e0.w;
                    n1 = (b1 + 1 < VPR) ? e4[b1 + 1].x : e1.w;
                    n2 = (b2 + 1 < VPR) ? e4[b2 + 1].x : e2.w;
                    n3 = (b3 + 1 < VPR) ? e4[b3 + 1].x : e3.w;
                }
                a2 += sq(e0.x - q0.x) + sq(e0.y - q0.y) + sq(e0.z - q0.z) + sq(e0.w - q0.w)
                    + sq(e1.x - q1.x) + sq(e1.y - q1.y) + sq(e1.z - q1.z) + sq(e1.w - q1.w)
                    + sq(e2.x - q2.x) + sq(e2.y - q2.y) + sq(e2.z - q2.z) + sq(e2.w - q2.w)
                    + sq(e3.x - q3.x) + sq(e3.y - q3.y) + sq(e3.z - q3.z) + sq(e3.w - q3.w);
                a3 += sq(e0.y - e0.x) + sq(e0.z - e0.y) + sq(e0.w - e0.z)
                    + sq(e1.y - e1.x) + sq(e1.z - e1.y) + sq(e1.w - e1.z)
                    + sq(e2.y - e2.x) + sq(e2.z - e2.y) + sq(e2.w - e2.z)
                    + sq(e3.y - e3.x) + sq(e3.z - e3.y) + sq(e3.w - e3.z);
                float s0 = __shfl_down(e0.x, 1, 64);
                float s1 = __shfl_down(e1.x, 1, 64);
                float s2 = __shfl_down(e2.x, 1, 64);
                float s3 = __shfl_down(e3.x, 1, 64);
                if (lane63) { s0 = n0; s1 = n1; s2 = n2; s3 = n3; }
                a3 += sq(s0 - e0.w) + sq(s1 - e1.w) + sq(s2 - e2.w) + sq(s3 - e3.w);
            }
            block_reduce2_store(a2, a3, dst);
        }
    }
}

// 256-thread finalize: reduce 2*2560 doubles, write the 4 outputs.
__global__ __launch_bounds__(THREADS)
void finalize_kernel(const double* __restrict__ ws,
                     const int* __restrict__ mask,
                     float* __restrict__ out) {
    const int tid = threadIdx.x;
    double s0 = 0.0, s1 = 0.0, s2 = 0.0, s3 = 0.0;
    #pragma unroll
    for (int k = 0; k < TOTAL_UNITS / THREADS; ++k) {
        const int i = k * THREADS + tid;
        double p = ws[2 * i], q = ws[2 * i + 1];
        if (i < RECON_UNITS) { s0 += p; s1 += q; }
        else                 { s2 += p; s3 += q; }
    }
    #pragma unroll
    for (int o = 32; o > 0; o >>= 1) {
        s0 += __shfl_down(s0, o, 64);
        s1 += __shfl_down(s1, o, 64);
        s2 += __shfl_down(s2, o, 64);
        s3 += __shfl_down(s3, o, 64);
    }
    __shared__ double lds[4][4];
    const int lane = tid & 63;
    const int wid  = tid >> 6;
    if (lane == 0) { lds[wid][0] = s0; lds[wid][1] = s1; lds[wid][2] = s2; lds[wid][3] = s3; }
    __syncthreads();
    if (tid == 0) {
        double t0 = lds[0][0] + lds[1][0] + lds[2][0] + lds[3][0];
        double t1 = lds[0][1] + lds[1][1] + lds[2][1] + lds[3][1];
        double t2 = lds[0][2] + lds[1][2] + lds[2][2] + lds[3][2];
        double t3 = lds[0][3] + lds[1][3] + lds[2][3] + lds[3][3];
        int c = 0;
        #pragma unroll
        for (int i = 0; i < kB * kN; ++i) c += (mask[i] == 1);
        double count = (double)c;
        double recon = t0 / (double)kBT + t1 / (double)kBT;
        double ifl   = t2 / (double)kBNT;
        double denom = (count > 1.0 ? count : 1.0) * (double)(kT - 1);
        double smooth = t3 / denom;
        double total = recon + LAMBDA_IF * ifl + (count > 0.0 ? LAMBDA_SMOOTH * smooth : 0.0);
        out[0] = (float)total;
        out[1] = (float)recon;
        out[2] = (float)ifl;
        out[3] = (float)smooth;
    }
}

extern "C" void kernel_launch(void* const* d_in, const int* in_sizes, int n_in,
                              void* d_out, int out_size, void* d_ws, size_t ws_size,
                              hipStream_t stream) {
    const float* rr  = (const float*)d_in[0];
    const float* ri  = (const float*)d_in[1];
    const float* tr  = (const float*)d_in[2];
    const float* ti  = (const float*)d_in[3];
    const float* eIF = (const float*)d_in[4];
    const float* tIF = (const float*)d_in[5];
    const int*   msk = (const int*)d_in[6];
    float* out = (float*)d_out;
    double* ws = (double*)d_ws;

    vncmd_main_kernel<<<GRID, THREADS, 0, stream>>>(
        rr, ri, tr, ti, eIF, tIF, msk, ws);
    finalize_kernel<<<1, THREADS, 0, stream>>>(ws, msk, out);
}